// Round 4
// baseline (497.221 us; speedup 1.0000x reference)
//
#include <hip/hip_runtime.h>
#include <hip/hip_bf16.h>

#define M_ROWS 17664   // B*T = 64*276
#define K_CODES 8192
#define D_DIM 256
#define N_ELEM 4521984 // M_ROWS * 256

typedef unsigned short ushort_t;
typedef __attribute__((ext_vector_type(8))) short short8v;  // 8 bf16 (4 VGPRs)
typedef __attribute__((ext_vector_type(4))) float f32x4;

__device__ __forceinline__ unsigned long long umin64(unsigned long long a, unsigned long long b) { return a < b ? a : b; }
__device__ __forceinline__ unsigned long long umax64(unsigned long long a, unsigned long long b) { return a > b ? a : b; }

__device__ __forceinline__ unsigned long long shflxor64(unsigned long long v, int m) {
    unsigned lo = (unsigned)v, hi = (unsigned)(v >> 32);
    lo = __shfl_xor(lo, m);
    hi = __shfl_xor(hi, m);
    return ((unsigned long long)hi << 32) | lo;
}
__device__ __forceinline__ unsigned long long shfl64(unsigned long long v, int src) {
    unsigned lo = (unsigned)v, hi = (unsigned)(v >> 32);
    lo = __shfl(lo, src);
    hi = __shfl(hi, src);
    return ((unsigned long long)hi << 32) | lo;
}

__device__ __forceinline__ void gload16(const void* g, void* l) {
    __builtin_amdgcn_global_load_lds((const __attribute__((address_space(1))) void*)g,
                                     (__attribute__((address_space(3))) void*)l, 16, 0, 0);
}

// ---------------------------------------------------------------------------
// Exact replication of numpy pairwise sum of squares for a 256-wide row.
// ---------------------------------------------------------------------------
__global__ void rowsq_kernel(const float* __restrict__ X,
                             float* __restrict__ out, int rows) {
    int r = blockIdx.x * blockDim.x + threadIdx.x;
    if (r >= rows) return;
    const float* p = X + (size_t)r * D_DIM;
    float half_sum[2];
#pragma unroll
    for (int h = 0; h < 2; ++h) {
        const float* q = p + h * 128;
        float acc[8];
#pragma unroll
        for (int j = 0; j < 8; ++j) acc[j] = __fmul_rn(q[j], q[j]);
        for (int i = 8; i < 128; i += 8) {
#pragma unroll
            for (int j = 0; j < 8; ++j)
                acc[j] = __fadd_rn(acc[j], __fmul_rn(q[i + j], q[i + j]));
        }
        float s01 = __fadd_rn(acc[0], acc[1]);
        float s23 = __fadd_rn(acc[2], acc[3]);
        float s45 = __fadd_rn(acc[4], acc[5]);
        float s67 = __fadd_rn(acc[6], acc[7]);
        half_sum[h] = __fadd_rn(__fadd_rn(s01, s23), __fadd_rn(s45, s67));
    }
    out[r] = __fadd_rn(half_sum[0], half_sum[1]);
}

__global__ void init_kernel(unsigned long long* __restrict__ packed,
                            float* __restrict__ loss_acc) {
    int i = blockIdx.x * blockDim.x + threadIdx.x;
    if (i < M_ROWS) packed[i] = 0xFFFFFFFFFFFFFFFFull;
    if (i == 0) loss_acc[0] = 0.0f;
}

__global__ void init_loss_kernel(float* __restrict__ loss_acc) {
    if (threadIdx.x == 0 && blockIdx.x == 0) loss_acc[0] = 0.0f;
}

// ---------------------------------------------------------------------------
// Split fp32 -> (hi, lo) bf16 pair. Out layout [row][512]: cols 0-255 = hi,
// 256-511 = lo.
// ---------------------------------------------------------------------------
__global__ void split_kernel(const float* __restrict__ X,
                             ushort_t* __restrict__ Xs, int rows) {
    int idx = blockIdx.x * blockDim.x + threadIdx.x;
    int total = rows * 64;
    if (idx >= total) return;
    int row = idx >> 6;
    int c4 = (idx & 63) * 4;
    float4 v = *(const float4*)(X + (size_t)row * D_DIM + c4);
    ushort_t h[4], l[4];
    float vv[4] = {v.x, v.y, v.z, v.w};
#pragma unroll
    for (int j = 0; j < 4; ++j) {
        __hip_bfloat16 b1 = __float2bfloat16(vv[j]);
        float bf = __bfloat162float(b1);
        float r = __fsub_rn(vv[j], bf);
        __hip_bfloat16 b2 = __float2bfloat16(r);
        h[j] = *reinterpret_cast<ushort_t*>(&b1);
        l[j] = *reinterpret_cast<ushort_t*>(&b2);
    }
    *(ushort4*)(Xs + (size_t)row * 512 + c4) = make_ushort4(h[0], h[1], h[2], h[3]);
    *(ushort4*)(Xs + (size_t)row * 512 + 256 + c4) = make_ushort4(l[0], l[1], l[2], l[3]);
}

// ---------------------------------------------------------------------------
// Phase 1: bf16 MFMA GEMM (Keff=768: z1c1 + z1c2 + z2c1), 128x128 tile,
// 4 waves (each 64x64), double-buffered global_load_lds staging (2-phase:
// issue-next-tile BEFORE compute, one __syncthreads per K-step), XOR-swizzled
// LDS (slot = quarter ^ ((row>>1)&3)) applied on BOTH the global source
// address (linear LDS dest, rule #21) and the ds_read slot -> 8-way bank
// conflict becomes free 2-way. Top-2 candidates per (row, 64-col group).
// ---------------------------------------------------------------------------
__global__ __launch_bounds__(256) void phase1_kernel(
    const ushort_t* __restrict__ Zs,   // [M][512] bf16 bits
    const ushort_t* __restrict__ Cs,   // [K][512] bf16 bits
    const float* __restrict__ asum, const float* __restrict__ bsum,
    unsigned long long* __restrict__ blockcand) {
    __shared__ ushort_t As[2][128 * 32];  // 2 x 8 KiB
    __shared__ ushort_t Bs[2][128 * 32];  // 2 x 8 KiB

    const int t = threadIdx.x;
    const int wid = t >> 6, lane = t & 63;
    const int bm = blockIdx.x / 64, bn = blockIdx.x % 64;  // 138 x 64
    const int m0 = bm * 128, n0 = bn * 128;
    const int wm = wid >> 1, wn = wid & 1;

    f32x4 acc[4][4];
#pragma unroll
    for (int i = 0; i < 4; ++i)
#pragma unroll
        for (int j = 0; j < 4; ++j) acc[i][j] = (f32x4){0.f, 0.f, 0.f, 0.f};

    // ---- staging source (pre-swizzled quarter; LDS dest stays linear) ----
    // lane l of chunk j: global row = 32*wid + 16*j + (l>>2);
    // source quarter = (l&3) ^ ((l>>3)&3)   [row-dependent term: rows that are
    // multiples of 16 contribute 0 to ((g>>1)&3), so only l>>2 low bits matter]
    const int srow = (lane >> 2);
    const int sq = ((lane & 3) ^ ((lane >> 3) & 3)) * 8;   // in shorts
    const ushort_t* Abase = Zs + (size_t)(m0 + 32 * wid + srow) * 512 + sq;
    const ushort_t* Bbase = Cs + (size_t)(n0 + 32 * wid + srow) * 512 + sq;
    const int ldsc0 = (wid * 2 + 0) * 512;   // shorts
    const int ldsc1 = (wid * 2 + 1) * 512;

    // ---- fragment read offsets (swizzled slot) ----
    // row g = {wm|wn}*64 + mi*16 + (lane&15); ((g>>1)&3) == ((lane>>1)&3)
    const int soff = ((lane >> 4) ^ ((lane >> 1) & 3)) * 8; // shorts
    int a_off[4], b_off[4];
#pragma unroll
    for (int mi = 0; mi < 4; ++mi)
        a_off[mi] = (wm * 64 + mi * 16 + (lane & 15)) * 32 + soff;
#pragma unroll
    for (int ni = 0; ni < 4; ++ni)
        b_off[ni] = (wn * 64 + ni * 16 + (lane & 15)) * 32 + soff;

    // ---- prologue: stage tile 0 into buf 0 ----
    gload16(Abase, &As[0][ldsc0]);
    gload16(Abase + 16 * 512, &As[0][ldsc1]);
    gload16(Bbase, &Bs[0][ldsc0]);
    gload16(Bbase + 16 * 512, &Bs[0][ldsc1]);
    __syncthreads();   // compiler drains vmcnt(0) before s_barrier

    // ---- main loop: 24 K-steps (3 segs x 8), fully unrolled ----
#pragma unroll 24
    for (int tt = 0; tt < 24; ++tt) {
        const int cur = tt & 1;
        if (tt < 23) {
            const int nt = tt + 1;
            const int nseg = nt >> 3;
            const int nk0 = (nt & 7) * 32;
            const int sa = ((nseg == 2) ? 256 : 0) + nk0;  // A: lo-half on seg 2
            const int sb = ((nseg == 1) ? 256 : 0) + nk0;  // B: lo-half on seg 1
            gload16(Abase + sa, &As[cur ^ 1][ldsc0]);
            gload16(Abase + 16 * 512 + sa, &As[cur ^ 1][ldsc1]);
            gload16(Bbase + sb, &Bs[cur ^ 1][ldsc0]);
            gload16(Bbase + 16 * 512 + sb, &Bs[cur ^ 1][ldsc1]);
        }
        short8v a[4], b[4];
#pragma unroll
        for (int mi = 0; mi < 4; ++mi)
            a[mi] = *(const short8v*)(&As[cur][a_off[mi]]);
#pragma unroll
        for (int ni = 0; ni < 4; ++ni)
            b[ni] = *(const short8v*)(&Bs[cur][b_off[ni]]);
        __builtin_amdgcn_s_setprio(1);
#pragma unroll
        for (int mi = 0; mi < 4; ++mi)
#pragma unroll
            for (int ni = 0; ni < 4; ++ni)
                acc[mi][ni] = __builtin_amdgcn_mfma_f32_16x16x32_bf16(
                    a[mi], b[ni], acc[mi][ni], 0, 0, 0);
        __builtin_amdgcn_s_setprio(0);
        // single barrier per K-step: waits this wave's prefetch (vmcnt->0) and
        // guarantees all waves finished reading buf[cur] before it's restaged.
        __syncthreads();
    }

    // ---- epilogue: per-row top-2 over this wave's 64 cols (fully unrolled) --
    unsigned long long* cand = (unsigned long long*)&As[0][0];  // [128][4] = 4 KiB
#pragma unroll
    for (int mi = 0; mi < 4; ++mi) {
#pragma unroll
        for (int r = 0; r < 4; ++r) {
            int lrow = wm * 64 + mi * 16 + (lane >> 4) * 4 + r;
            float ar = asum[m0 + lrow];
            unsigned long long b1 = 0xFFFFFFFFFFFFFFFFull, b2 = 0xFFFFFFFFFFFFFFFFull;
#pragma unroll
            for (int ni = 0; ni < 4; ++ni) {
                int lcol = wn * 64 + ni * 16 + (lane & 15);
                float bc = bsum[n0 + lcol];
                float dt = (ar + bc) - 2.0f * acc[mi][ni][r];
                unsigned long long p =
                    ((unsigned long long)__float_as_uint(dt) << 32) | (unsigned)(n0 + lcol);
                unsigned long long nb1 = umin64(b1, p);
                unsigned long long nb2 = umin64(b2, umax64(b1, p));
                b1 = nb1; b2 = nb2;
            }
#pragma unroll
            for (int s = 1; s < 16; s <<= 1) {
                unsigned long long o1 = shflxor64(b1, s);
                unsigned long long o2 = shflxor64(b2, s);
                unsigned long long n1 = umin64(b1, o1);
                unsigned long long n2 = umin64(umax64(b1, o1), umin64(b2, o2));
                b1 = n1; b2 = n2;
            }
            if ((lane & 15) == 0) {
                cand[(size_t)lrow * 4 + wn * 2 + 0] = b1;
                cand[(size_t)lrow * 4 + wn * 2 + 1] = b2;
            }
        }
    }
    __syncthreads();
    // coalesced write: blockcand[row][group=bn*2+wn][2]
    {
        int row = t >> 1, pair = t & 1;
        unsigned long long v0 = cand[(size_t)row * 4 + pair * 2 + 0];
        unsigned long long v1 = cand[(size_t)row * 4 + pair * 2 + 1];
        unsigned long long* dst =
            blockcand + (size_t)(m0 + row) * 256 + (size_t)bn * 4 + pair * 2;
        dst[0] = v0; dst[1] = v1;
    }
}

// ---------------------------------------------------------------------------
// Phase 2 + finalize: per row (one wave), threshold-scan 256 candidates,
// exact fp32 quantized distance per survivor (np-structured), index tiebreak,
// then z_q_st / min_idx / loss exactly as round-1.
// ---------------------------------------------------------------------------
__global__ __launch_bounds__(256) void phase2_kernel(
    const float* __restrict__ Z, const float* __restrict__ CB,
    const float* __restrict__ asum, const float* __restrict__ bsum,
    const unsigned long long* __restrict__ blockcand,
    float* __restrict__ out, float* __restrict__ loss_acc) {
    float* out_zq = out + 2;
    float* out_idx = out + 2 + (size_t)N_ELEM;
    const int lane = threadIdx.x & 63;
    const int w = threadIdx.x >> 6;
    const int row = blockIdx.x * 4 + w;
    float lsum = 0.0f;

    if (row < M_ROWS) {
        const unsigned long long* cr = blockcand + (size_t)row * 256;
        unsigned long long e0 = cr[lane], e1 = cr[lane + 64];
        unsigned long long e2 = cr[lane + 128], e3 = cr[lane + 192];
        unsigned long long mn = umin64(umin64(e0, e1), umin64(e2, e3));
#pragma unroll
        for (int s = 1; s < 64; s <<= 1) mn = umin64(mn, shflxor64(mn, s));
        float dmin = __uint_as_float((unsigned)(mn >> 32));
        float thr = dmin + 8.0e-5f;
        unsigned long long m0m = __ballot(__uint_as_float((unsigned)(e0 >> 32)) <= thr);
        unsigned long long m1m = __ballot(__uint_as_float((unsigned)(e1 >> 32)) <= thr);
        unsigned long long m2m = __ballot(__uint_as_float((unsigned)(e2 >> 32)) <= thr);
        unsigned long long m3m = __ballot(__uint_as_float((unsigned)(e3 >> 32)) <= thr);

        const float4 zv = *(const float4*)(Z + (size_t)row * D_DIM + lane * 4);
        float ar = asum[row];
        unsigned long long best = 0xFFFFFFFFFFFFFFFFull;

        while (m0m | m1m | m2m | m3m) {
            unsigned long long e;
            if (m0m)      { int b = __ffsll((unsigned long long)m0m) - 1; m0m &= m0m - 1; e = shfl64(e0, b); }
            else if (m1m) { int b = __ffsll((unsigned long long)m1m) - 1; m1m &= m1m - 1; e = shfl64(e1, b); }
            else if (m2m) { int b = __ffsll((unsigned long long)m2m) - 1; m2m &= m2m - 1; e = shfl64(e2, b); }
            else          { int b = __ffsll((unsigned long long)m3m) - 1; m3m &= m3m - 1; e = shfl64(e3, b); }
            unsigned col = (unsigned)e;
            const float4 cv = *(const float4*)(CB + (size_t)col * D_DIM + lane * 4);
            float s = __fmul_rn(zv.x, cv.x);
            s = __builtin_fmaf(zv.y, cv.y, s);
            s = __builtin_fmaf(zv.z, cv.z, s);
            s = __builtin_fmaf(zv.w, cv.w, s);
#pragma unroll
            for (int m = 1; m < 64; m <<= 1) s += __shfl_xor(s, m);
            float d = __fsub_rn(__fadd_rn(ar, bsum[col]), __fmul_rn(2.0f, s));
            unsigned long long p = ((unsigned long long)__float_as_uint(d) << 32) | col;
            best = umin64(best, p);
        }

        unsigned wincol = (unsigned)best;
        if (lane == 0) out_idx[row] = (float)wincol;
        const float4 cv = *(const float4*)(CB + (size_t)wincol * D_DIM + lane * 4);
        float d0 = __fsub_rn(cv.x, zv.x);
        float d1 = __fsub_rn(cv.y, zv.y);
        float d2 = __fsub_rn(cv.z, zv.z);
        float d3 = __fsub_rn(cv.w, zv.w);
        float2 o0 = make_float2(__fadd_rn(zv.x, d0), __fadd_rn(zv.y, d1));
        float2 o1 = make_float2(__fadd_rn(zv.z, d2), __fadd_rn(zv.w, d3));
        *(float2*)(out_zq + (size_t)row * D_DIM + lane * 4) = o0;
        *(float2*)(out_zq + (size_t)row * D_DIM + lane * 4 + 2) = o1;
        lsum = d0 * d0 + d1 * d1 + d2 * d2 + d3 * d3;
    }
#pragma unroll
    for (int m = 1; m < 64; m <<= 1) lsum += __shfl_xor(lsum, m);
    __shared__ float red[4];
    if (lane == 0) red[w] = lsum;
    __syncthreads();
    if (threadIdx.x == 0) {
        float s = ((red[0] + red[1]) + (red[2] + red[3]));
        atomicAdd(loss_acc, s);
    }
}

__global__ void write_losses(const float* __restrict__ loss_acc,
                             float* __restrict__ out) {
    float l = __fdiv_rn(loss_acc[0], (float)N_ELEM);
    out[0] = l;
    out[1] = l;
}

// ======================= round-1 fallback (fp32 VALU) =======================
#define BM 128
#define BN 128
#define BK 32
#define LDT 132

__global__ __launch_bounds__(256) void gemm_argmin_kernel(
    const float* __restrict__ Z, const float* __restrict__ CB,
    const float* __restrict__ asum, const float* __restrict__ bsum,
    unsigned long long* __restrict__ packed) {
    __shared__ float As[BK][LDT];
    __shared__ float Bs[BK][LDT];
    const int bid = blockIdx.x;
    const int bm = bid >> 6, bn = bid & 63;
    const int m0 = bm * BM, n0 = bn * BN;
    const int t = threadIdx.x;
    const int ty = t >> 4, tx = t & 15;
    float acc[8][8];
#pragma unroll
    for (int i = 0; i < 8; ++i)
#pragma unroll
        for (int j = 0; j < 8; ++j) acc[i][j] = 0.0f;
    for (int k0 = 0; k0 < D_DIM; k0 += BK) {
#pragma unroll
        for (int i = 0; i < 4; ++i) {
            int idx = t + i * 256;
            int row = idx >> 3, kq = idx & 7;
            const float4 av = *(const float4*)(Z + (size_t)(m0 + row) * D_DIM + k0 + kq * 4);
            As[kq * 4 + 0][row] = av.x; As[kq * 4 + 1][row] = av.y;
            As[kq * 4 + 2][row] = av.z; As[kq * 4 + 3][row] = av.w;
            const float4 bv = *(const float4*)(CB + (size_t)(n0 + row) * D_DIM + k0 + kq * 4);
            Bs[kq * 4 + 0][row] = bv.x; Bs[kq * 4 + 1][row] = bv.y;
            Bs[kq * 4 + 2][row] = bv.z; Bs[kq * 4 + 3][row] = bv.w;
        }
        __syncthreads();
#pragma unroll
        for (int k = 0; k < BK; ++k) {
            float af[8], bf[8];
            *(float4*)(af)     = *(const float4*)(&As[k][ty * 4]);
            *(float4*)(af + 4) = *(const float4*)(&As[k][64 + ty * 4]);
            *(float4*)(bf)     = *(const float4*)(&Bs[k][tx * 4]);
            *(float4*)(bf + 4) = *(const float4*)(&Bs[k][64 + tx * 4]);
#pragma unroll
            for (int i = 0; i < 8; ++i)
#pragma unroll
                for (int j = 0; j < 8; ++j)
                    acc[i][j] = __builtin_fmaf(af[i], bf[j], acc[i][j]);
        }
        __syncthreads();
    }
    float ar[8], bc[8];
    int rowIdx[8], colIdx[8];
#pragma unroll
    for (int i = 0; i < 8; ++i) {
        rowIdx[i] = (i < 4) ? (4 * ty + i) : (64 + 4 * ty + (i - 4));
        ar[i] = asum[m0 + rowIdx[i]];
    }
#pragma unroll
    for (int j = 0; j < 8; ++j) {
        colIdx[j] = (j < 4) ? (4 * tx + j) : (64 + 4 * tx + (j - 4));
        bc[j] = bsum[n0 + colIdx[j]];
    }
#pragma unroll
    for (int i = 0; i < 8; ++i) {
        unsigned long long best = 0xFFFFFFFFFFFFFFFFull;
#pragma unroll
        for (int j = 0; j < 8; ++j) {
            float ts = __fadd_rn(ar[i], bc[j]);
            float d = __fsub_rn(ts, __fmul_rn(2.0f, acc[i][j]));
            unsigned long long p = ((unsigned long long)__float_as_uint(d) << 32) |
                                   (unsigned)(n0 + colIdx[j]);
            best = (p < best) ? p : best;
        }
#pragma unroll
        for (int m = 1; m <= 8; m <<= 1) {
            unsigned long long o = shflxor64(best, m);
            best = (o < best) ? o : best;
        }
        if (tx == 0) atomicMin(&packed[m0 + rowIdx[i]], best);
    }
}

__global__ __launch_bounds__(256) void finalize_kernel(
    const float* __restrict__ Z, const float* __restrict__ CB,
    const unsigned long long* __restrict__ packed,
    float* __restrict__ out, float* __restrict__ loss_acc) {
    float* out_zq = out + 2;
    float* out_idx = out + 2 + (size_t)N_ELEM;
    const int lane = threadIdx.x & 63;
    const int wid = (blockIdx.x * blockDim.x + threadIdx.x) >> 6;
    const int nw = (gridDim.x * blockDim.x) >> 6;
    float lsum = 0.0f;
    for (int row = wid; row < M_ROWS; row += nw) {
        unsigned long long pk = packed[row];
        unsigned idx = (unsigned)(pk & 0xFFFFFFFFull);
        if (lane == 0) out_idx[row] = (float)idx;
        const float4 zv = *(const float4*)(Z + (size_t)row * D_DIM + lane * 4);
        const float4 cv = *(const float4*)(CB + (size_t)idx * D_DIM + lane * 4);
        float d0 = __fsub_rn(cv.x, zv.x);
        float d1 = __fsub_rn(cv.y, zv.y);
        float d2 = __fsub_rn(cv.z, zv.z);
        float d3 = __fsub_rn(cv.w, zv.w);
        float2 o0 = make_float2(__fadd_rn(zv.x, d0), __fadd_rn(zv.y, d1));
        float2 o1 = make_float2(__fadd_rn(zv.z, d2), __fadd_rn(zv.w, d3));
        *(float2*)(out_zq + (size_t)row * D_DIM + lane * 4) = o0;
        *(float2*)(out_zq + (size_t)row * D_DIM + lane * 4 + 2) = o1;
        lsum += d0 * d0 + d1 * d1 + d2 * d2 + d3 * d3;
    }
#pragma unroll
    for (int m = 1; m < 64; m <<= 1) lsum += __shfl_xor(lsum, m);
    __shared__ float red[4];
    if (lane == 0) red[threadIdx.x >> 6] = lsum;
    __syncthreads();
    if (threadIdx.x == 0) {
        float s = ((red[0] + red[1]) + (red[2] + red[3]));
        atomicAdd(loss_acc, s);
    }
}

// ===========================================================================
extern "C" void kernel_launch(void* const* d_in, const int* in_sizes, int n_in,
                              void* d_out, int out_size, void* d_ws, size_t ws_size,
                              hipStream_t stream) {
    const float* Z = (const float*)d_in[0];    // [17664, 256]
    const float* CB = (const float*)d_in[1];   // [8192, 256]
    float* out = (float*)d_out;
    char* ws = (char*)d_ws;

    const size_t offZs   = 0;
    const size_t offCs   = offZs + (size_t)M_ROWS * 512 * 2;
    const size_t offCand = offCs + (size_t)K_CODES * 512 * 2;
    const size_t offAsum = offCand + (size_t)M_ROWS * 256 * 8;
    const size_t offBsum = offAsum + (size_t)M_ROWS * 4;
    const size_t offLoss = offBsum + (size_t)K_CODES * 4;
    const size_t need    = offLoss + 64;

    if (ws_size >= need) {
        ushort_t* Zs = (ushort_t*)(ws + offZs);
        ushort_t* Cs = (ushort_t*)(ws + offCs);
        unsigned long long* blockcand = (unsigned long long*)(ws + offCand);
        float* asum = (float*)(ws + offAsum);
        float* bsum = (float*)(ws + offBsum);
        float* loss_acc = (float*)(ws + offLoss);

        hipLaunchKernelGGL(init_loss_kernel, dim3(1), dim3(64), 0, stream, loss_acc);
        hipLaunchKernelGGL(rowsq_kernel, dim3((M_ROWS + 255) / 256), dim3(256), 0, stream,
                           Z, asum, M_ROWS);
        hipLaunchKernelGGL(rowsq_kernel, dim3((K_CODES + 255) / 256), dim3(256), 0, stream,
                           CB, bsum, K_CODES);
        hipLaunchKernelGGL(split_kernel, dim3((M_ROWS * 64 + 255) / 256), dim3(256), 0, stream,
                           Z, Zs, M_ROWS);
        hipLaunchKernelGGL(split_kernel, dim3((K_CODES * 64 + 255) / 256), dim3(256), 0, stream,
                           CB, Cs, K_CODES);
        hipLaunchKernelGGL(phase1_kernel, dim3((M_ROWS / 128) * (K_CODES / 128)),
                           dim3(256), 0, stream, Zs, Cs, asum, bsum, blockcand);
        hipLaunchKernelGGL(phase2_kernel, dim3(M_ROWS / 4), dim3(256), 0, stream,
                           Z, CB, asum, bsum, blockcand, out, loss_acc);
        hipLaunchKernelGGL(write_losses, dim3(1), dim3(1), 0, stream, loss_acc, out);
    } else {
        float* asum = (float*)ws;
        float* bsum = (float*)(ws + (size_t)M_ROWS * 4);
        unsigned long long* packed =
            (unsigned long long*)(ws + (size_t)M_ROWS * 4 + (size_t)K_CODES * 4);
        float* loss_acc =
            (float*)(ws + (size_t)M_ROWS * 4 + (size_t)K_CODES * 4 + (size_t)M_ROWS * 8);

        hipLaunchKernelGGL(init_kernel, dim3((M_ROWS + 255) / 256), dim3(256), 0, stream,
                           packed, loss_acc);
        hipLaunchKernelGGL(rowsq_kernel, dim3((M_ROWS + 255) / 256), dim3(256), 0, stream,
                           Z, asum, M_ROWS);
        hipLaunchKernelGGL(rowsq_kernel, dim3((K_CODES + 255) / 256), dim3(256), 0, stream,
                           CB, bsum, K_CODES);
        hipLaunchKernelGGL(gemm_argmin_kernel, dim3((M_ROWS / BM) * (K_CODES / BN)),
                           dim3(256), 0, stream, Z, CB, asum, bsum, packed);
        hipLaunchKernelGGL(finalize_kernel, dim3(512), dim3(256), 0, stream,
                           Z, CB, packed, out, loss_acc);
        hipLaunchKernelGGL(write_losses, dim3(1), dim3(1), 0, stream, loss_acc, out);
    }
}

// Round 5
// 196.324 us; speedup vs baseline: 2.5327x; 2.5327x over previous
//
#include <hip/hip_runtime.h>
#include <hip/hip_bf16.h>

#define M_ROWS 17664   // B*T = 64*276
#define K_CODES 8192
#define D_DIM 256
#define N_ELEM 4521984 // M_ROWS * 256

typedef unsigned short ushort_t;
typedef __attribute__((ext_vector_type(8))) short short8v;  // 8 bf16 (4 VGPRs)
typedef __attribute__((ext_vector_type(4))) float f32x4;

__device__ __forceinline__ unsigned long long umin64(unsigned long long a, unsigned long long b) { return a < b ? a : b; }
__device__ __forceinline__ unsigned long long umax64(unsigned long long a, unsigned long long b) { return a > b ? a : b; }

__device__ __forceinline__ unsigned long long shflxor64(unsigned long long v, int m) {
    unsigned lo = (unsigned)v, hi = (unsigned)(v >> 32);
    lo = __shfl_xor(lo, m);
    hi = __shfl_xor(hi, m);
    return ((unsigned long long)hi << 32) | lo;
}

__device__ __forceinline__ void gload16(const void* g, void* l) {
    __builtin_amdgcn_global_load_lds((const __attribute__((address_space(1))) void*)g,
                                     (__attribute__((address_space(3))) void*)l, 16, 0, 0);
}

// ---------------------------------------------------------------------------
// Exact replication of numpy pairwise sum of squares for a 256-wide row.
// ---------------------------------------------------------------------------
__global__ void rowsq_kernel(const float* __restrict__ X,
                             float* __restrict__ out, int rows) {
    int r = blockIdx.x * blockDim.x + threadIdx.x;
    if (r >= rows) return;
    const float* p = X + (size_t)r * D_DIM;
    float half_sum[2];
#pragma unroll
    for (int h = 0; h < 2; ++h) {
        const float* q = p + h * 128;
        float acc[8];
#pragma unroll
        for (int j = 0; j < 8; ++j) acc[j] = __fmul_rn(q[j], q[j]);
        for (int i = 8; i < 128; i += 8) {
#pragma unroll
            for (int j = 0; j < 8; ++j)
                acc[j] = __fadd_rn(acc[j], __fmul_rn(q[i + j], q[i + j]));
        }
        float s01 = __fadd_rn(acc[0], acc[1]);
        float s23 = __fadd_rn(acc[2], acc[3]);
        float s45 = __fadd_rn(acc[4], acc[5]);
        float s67 = __fadd_rn(acc[6], acc[7]);
        half_sum[h] = __fadd_rn(__fadd_rn(s01, s23), __fadd_rn(s45, s67));
    }
    out[r] = __fadd_rn(half_sum[0], half_sum[1]);
}

__global__ void init_kernel(unsigned long long* __restrict__ packed,
                            float* __restrict__ loss_acc) {
    int i = blockIdx.x * blockDim.x + threadIdx.x;
    if (i < M_ROWS) packed[i] = 0xFFFFFFFFFFFFFFFFull;
    if (i == 0) loss_acc[0] = 0.0f;
}

__global__ void init_loss_kernel(float* __restrict__ loss_acc) {
    if (threadIdx.x == 0 && blockIdx.x == 0) loss_acc[0] = 0.0f;
}

// ---------------------------------------------------------------------------
// fp32 -> bf16 (RNE) convert, 8 elems/thread.
// ---------------------------------------------------------------------------
__global__ void tobf16_kernel(const float* __restrict__ X,
                              ushort_t* __restrict__ Xb, int n8) {
    int i = blockIdx.x * blockDim.x + threadIdx.x;
    if (i >= n8) return;
    const float4 v0 = *(const float4*)(X + (size_t)i * 8);
    const float4 v1 = *(const float4*)(X + (size_t)i * 8 + 4);
    float vv[8] = {v0.x, v0.y, v0.z, v0.w, v1.x, v1.y, v1.z, v1.w};
    ushort_t h[8];
#pragma unroll
    for (int j = 0; j < 8; ++j) {
        __hip_bfloat16 b = __float2bfloat16(vv[j]);
        h[j] = *reinterpret_cast<ushort_t*>(&b);
    }
    *(ushort4*)(Xb + (size_t)i * 8) = make_ushort4(h[0], h[1], h[2], h[3]);
    *(ushort4*)(Xb + (size_t)i * 8 + 4) = make_ushort4(h[4], h[5], h[6], h[7]);
}

// ---------------------------------------------------------------------------
// Phase 1: plain-bf16 MFMA GEMM (Keff=256), 256x256 tile, 8 waves (2Mz x 4Ncb),
// K-chunk=64, double-buffered 128KiB LDS, counted s_waitcnt vmcnt(8) + raw
// s_barrier (prefetch stays in flight across the barrier). XOR-swizzled LDS
// (phys_slot = log_slot ^ (row&7)) applied on BOTH the pre-swizzled global
// source (linear gload_lds dest, rule #21) and the ds_read slot.
// SWAPPED operands: mfma(a=cb_frag, b=z_frag) so acc rows = codebook cols ->
// each lane holds 16 cb-candidates (4 mi x 4 reg) for ONE z-row; group top-2
// = per-lane min/med3 chain + 2-step shuffle merge. The 13-bit col index is
// embedded in the cleared low mantissa of d_rel = ||c||^2 - 2 z.c
// (|d_rel| <= ~0.012 -> embed quantum <= 7.6e-6, covered by phase-2 margin;
// ties keep both entries so order is irrelevant).
// Output: blockcand[row][128 groups][2] u32 (embedded floats).
// ---------------------------------------------------------------------------
__global__ __launch_bounds__(512, 2) void phase1_kernel(
    const ushort_t* __restrict__ Zb,   // [M][256] bf16 bits
    const ushort_t* __restrict__ Cb,   // [K][256] bf16 bits
    const float* __restrict__ bsum,
    unsigned* __restrict__ blockcand) {
    extern __shared__ ushort_t lds[];  // 131072 B: As[2][16384], Bs[2][16384]
    ushort_t* Asl = lds;               // z tiles
    ushort_t* Bsl = lds + 32768;       // cb tiles

    const int t = threadIdx.x;
    const int wid = t >> 6, lane = t & 63;
    const int wm = wid >> 2, wn = wid & 3;

    // XCD-grouped mapping: 4 bn-tiles per XCD (B-panel L2-resident),
    // A-panel gets 4x temporal reuse. Bijective: 2208 = 8 * 276, 276 = 69*4.
    const int bid = blockIdx.x;
    const int xcd = bid & 7, j = bid >> 3;
    const int bn = (xcd << 2) + (j & 3);
    const int bm = j >> 2;
    const int m0 = bm * 256, n0 = bn * 256;

    f32x4 acc[4][8];
#pragma unroll
    for (int i = 0; i < 4; ++i)
#pragma unroll
        for (int jj = 0; jj < 8; ++jj) acc[i][jj] = (f32x4){0.f, 0.f, 0.f, 0.f};

    // staging source (pre-swizzled slot): issue i covers rows wid*32+i*8+(l>>3)
    const int sq8 = ((lane & 7) ^ (lane >> 3)) * 8;      // shorts
    const ushort_t* zsrc = Zb + (size_t)(m0 + wid * 32 + (lane >> 3)) * 256 + sq8;
    const ushort_t* csrc = Cb + (size_t)(n0 + wid * 32 + (lane >> 3)) * 256 + sq8;
    const int ldst = (wid * 32) * 64;                    // shorts, + i*512

    // fragment read geometry
    const int fr = lane & 15, x7 = lane & 7, q = lane >> 4;

    // ---- prologue: stage chunk 0 -> buf 0 (8 gloads/thread) ----
#pragma unroll
    for (int i = 0; i < 4; ++i) {
        gload16(zsrc + (size_t)i * 2048, Asl + ldst + i * 512);
        gload16(csrc + (size_t)i * 2048, Bsl + ldst + i * 512);
    }

#pragma unroll
    for (int c = 0; c < 4; ++c) {
        const int buf = c & 1;
        if (c < 3) {
            const int kc2 = (c + 1) * 64;
            const int ob = (buf ^ 1) * 16384;
#pragma unroll
            for (int i = 0; i < 4; ++i) {
                gload16(zsrc + (size_t)i * 2048 + kc2, Asl + ob + ldst + i * 512);
                gload16(csrc + (size_t)i * 2048 + kc2, Bsl + ob + ldst + i * 512);
            }
            asm volatile("s_waitcnt vmcnt(8)" ::: "memory");
        } else {
            asm volatile("s_waitcnt vmcnt(0)" ::: "memory");
        }
        __builtin_amdgcn_s_barrier();
        asm volatile("" ::: "memory");

        const ushort_t* Az = Asl + buf * 16384;
        const ushort_t* Bc = Bsl + buf * 16384;
#pragma unroll
        for (int ks = 0; ks < 2; ++ks) {
            const int phys = (((q + ks * 4)) ^ x7) * 8;  // shorts
            short8v acb[4], bz[8];
#pragma unroll
            for (int mi = 0; mi < 4; ++mi)
                acb[mi] = *(const short8v*)(Bc + (wn * 64 + mi * 16 + fr) * 64 + phys);
#pragma unroll
            for (int nj = 0; nj < 8; ++nj)
                bz[nj] = *(const short8v*)(Az + (wm * 128 + nj * 16 + fr) * 64 + phys);
            __builtin_amdgcn_s_setprio(1);
#pragma unroll
            for (int mi = 0; mi < 4; ++mi)
#pragma unroll
                for (int nj = 0; nj < 8; ++nj)
                    acc[mi][nj] = __builtin_amdgcn_mfma_f32_16x16x32_bf16(
                        acb[mi], bz[nj], acc[mi][nj], 0, 0, 0);
            __builtin_amdgcn_s_setprio(0);
        }
        if (c < 3) {
            asm volatile("" ::: "memory");
            __builtin_amdgcn_s_barrier();
        }
    }

    // ---- epilogue: per z-row top-2 over this wave's 64 cb-cols ----
    const int colb = n0 + wn * 64 + q * 4;   // per-lane col base
    float bc16[16];
#pragma unroll
    for (int mi = 0; mi < 4; ++mi)
#pragma unroll
        for (int r = 0; r < 4; ++r)
            bc16[mi * 4 + r] = bsum[colb + mi * 16 + r];

    const float INF = __uint_as_float(0x7f800000u);
#pragma unroll
    for (int nj = 0; nj < 8; ++nj) {
        float m1 = INF, m2 = INF;
#pragma unroll
        for (int mi = 0; mi < 4; ++mi)
#pragma unroll
            for (int r = 0; r < 4; ++r) {
                float dm = __builtin_fmaf(-2.0f, acc[mi][nj][r], bc16[mi * 4 + r]);
                unsigned e = (__float_as_uint(dm) & 0xFFFFE000u) |
                             (unsigned)(colb + mi * 16 + r);
                float fe = __uint_as_float(e);
                m2 = __builtin_amdgcn_fmed3f(m1, m2, fe);  // 2nd-smallest update
                m1 = fminf(m1, fe);
            }
        // merge across lanes {l, l+16, l+32, l+48}
#pragma unroll
        for (int s = 16; s <= 32; s <<= 1) {
            float o1 = __shfl_xor(m1, s);
            float o2 = __shfl_xor(m2, s);
            float nm2 = fminf(fmaxf(m1, o1), fminf(m2, o2));
            m1 = fminf(m1, o1);
            m2 = nm2;
        }
        if (q == 0) {
            int zr = m0 + wm * 128 + nj * 16 + fr;
            *(uint2*)(blockcand + (size_t)zr * 256 + (size_t)bn * 8 + wn * 2) =
                make_uint2(__float_as_uint(m1), __float_as_uint(m2));
        }
    }
}

// ---------------------------------------------------------------------------
// Phase 2 + finalize: per row (one wave), scan 256 u32 candidates, threshold
// at dmin_rel + 5e-4 (covers bf16 error + embed quantum + np-bin), exact fp32
// np-structured distance per survivor, index tiebreak, then z_q_st / min_idx /
// loss exactly as the verified round-1 path.
// ---------------------------------------------------------------------------
__global__ __launch_bounds__(256) void phase2_kernel(
    const float* __restrict__ Z, const float* __restrict__ CB,
    const float* __restrict__ asum, const float* __restrict__ bsum,
    const unsigned* __restrict__ blockcand,
    float* __restrict__ out, float* __restrict__ loss_acc) {
    float* out_zq = out + 2;
    float* out_idx = out + 2 + (size_t)N_ELEM;
    const int lane = threadIdx.x & 63;
    const int w = threadIdx.x >> 6;
    const int row = blockIdx.x * 4 + w;
    float lsum = 0.0f;

    if (row < M_ROWS) {
        const uint4 E = ((const uint4*)(blockcand + (size_t)row * 256))[lane];
        float f0 = __uint_as_float(E.x), f1 = __uint_as_float(E.y);
        float f2 = __uint_as_float(E.z), f3 = __uint_as_float(E.w);
        float mn = fminf(fminf(f0, f1), fminf(f2, f3));
#pragma unroll
        for (int s = 1; s < 64; s <<= 1) mn = fminf(mn, __shfl_xor(mn, s));
        const float thr = mn + 5.0e-4f;
        unsigned long long k0m = __ballot(f0 <= thr);
        unsigned long long k1m = __ballot(f1 <= thr);
        unsigned long long k2m = __ballot(f2 <= thr);
        unsigned long long k3m = __ballot(f3 <= thr);

        const float4 zv = *(const float4*)(Z + (size_t)row * D_DIM + lane * 4);
        float ar = asum[row];
        unsigned long long best = 0xFFFFFFFFFFFFFFFFull;

        while (k0m | k1m | k2m | k3m) {
            unsigned e;
            if (k0m)      { int b = __ffsll(k0m) - 1; k0m &= k0m - 1; e = __shfl(E.x, b); }
            else if (k1m) { int b = __ffsll(k1m) - 1; k1m &= k1m - 1; e = __shfl(E.y, b); }
            else if (k2m) { int b = __ffsll(k2m) - 1; k2m &= k2m - 1; e = __shfl(E.z, b); }
            else          { int b = __ffsll(k3m) - 1; k3m &= k3m - 1; e = __shfl(E.w, b); }
            unsigned col = e & 8191u;
            const float4 cv = *(const float4*)(CB + (size_t)col * D_DIM + lane * 4);
            float s = __fmul_rn(zv.x, cv.x);
            s = __builtin_fmaf(zv.y, cv.y, s);
            s = __builtin_fmaf(zv.z, cv.z, s);
            s = __builtin_fmaf(zv.w, cv.w, s);
#pragma unroll
            for (int m = 1; m < 64; m <<= 1) s += __shfl_xor(s, m);
            float d = __fsub_rn(__fadd_rn(ar, bsum[col]), __fmul_rn(2.0f, s));
            unsigned long long p = ((unsigned long long)__float_as_uint(d) << 32) | col;
            best = umin64(best, p);
        }

        unsigned wincol = (unsigned)best;
        if (lane == 0) out_idx[row] = (float)wincol;
        const float4 cv = *(const float4*)(CB + (size_t)wincol * D_DIM + lane * 4);
        float d0 = __fsub_rn(cv.x, zv.x);
        float d1 = __fsub_rn(cv.y, zv.y);
        float d2 = __fsub_rn(cv.z, zv.z);
        float d3 = __fsub_rn(cv.w, zv.w);
        float2 o0 = make_float2(__fadd_rn(zv.x, d0), __fadd_rn(zv.y, d1));
        float2 o1 = make_float2(__fadd_rn(zv.z, d2), __fadd_rn(zv.w, d3));
        *(float2*)(out_zq + (size_t)row * D_DIM + lane * 4) = o0;
        *(float2*)(out_zq + (size_t)row * D_DIM + lane * 4 + 2) = o1;
        lsum = d0 * d0 + d1 * d1 + d2 * d2 + d3 * d3;
    }
#pragma unroll
    for (int m = 1; m < 64; m <<= 1) lsum += __shfl_xor(lsum, m);
    __shared__ float red[4];
    if (lane == 0) red[w] = lsum;
    __syncthreads();
    if (threadIdx.x == 0) {
        float s = ((red[0] + red[1]) + (red[2] + red[3]));
        atomicAdd(loss_acc, s);
    }
}

__global__ void write_losses(const float* __restrict__ loss_acc,
                             float* __restrict__ out) {
    float l = __fdiv_rn(loss_acc[0], (float)N_ELEM);
    out[0] = l;
    out[1] = l;
}

// ======================= round-1 fallback (fp32 VALU) =======================
#define BM 128
#define BN 128
#define BK 32
#define LDT 132

__global__ __launch_bounds__(256) void gemm_argmin_kernel(
    const float* __restrict__ Z, const float* __restrict__ CB,
    const float* __restrict__ asum, const float* __restrict__ bsum,
    unsigned long long* __restrict__ packed) {
    __shared__ float As[BK][LDT];
    __shared__ float Bs[BK][LDT];
    const int bid = blockIdx.x;
    const int bm = bid >> 6, bn = bid & 63;
    const int m0 = bm * BM, n0 = bn * BN;
    const int t = threadIdx.x;
    const int ty = t >> 4, tx = t & 15;
    float acc[8][8];
#pragma unroll
    for (int i = 0; i < 8; ++i)
#pragma unroll
        for (int j = 0; j < 8; ++j) acc[i][j] = 0.0f;
    for (int k0 = 0; k0 < D_DIM; k0 += BK) {
#pragma unroll
        for (int i = 0; i < 4; ++i) {
            int idx = t + i * 256;
            int row = idx >> 3, kq = idx & 7;
            const float4 av = *(const float4*)(Z + (size_t)(m0 + row) * D_DIM + k0 + kq * 4);
            As[kq * 4 + 0][row] = av.x; As[kq * 4 + 1][row] = av.y;
            As[kq * 4 + 2][row] = av.z; As[kq * 4 + 3][row] = av.w;
            const float4 bv = *(const float4*)(CB + (size_t)(n0 + row) * D_DIM + k0 + kq * 4);
            Bs[kq * 4 + 0][row] = bv.x; Bs[kq * 4 + 1][row] = bv.y;
            Bs[kq * 4 + 2][row] = bv.z; Bs[kq * 4 + 3][row] = bv.w;
        }
        __syncthreads();
#pragma unroll
        for (int k = 0; k < BK; ++k) {
            float af[8], bf[8];
            *(float4*)(af)     = *(const float4*)(&As[k][ty * 4]);
            *(float4*)(af + 4) = *(const float4*)(&As[k][64 + ty * 4]);
            *(float4*)(bf)     = *(const float4*)(&Bs[k][tx * 4]);
            *(float4*)(bf + 4) = *(const float4*)(&Bs[k][64 + tx * 4]);
#pragma unroll
            for (int i = 0; i < 8; ++i)
#pragma unroll
                for (int j = 0; j < 8; ++j)
                    acc[i][j] = __builtin_fmaf(af[i], bf[j], acc[i][j]);
        }
        __syncthreads();
    }
    float ar[8], bc[8];
    int rowIdx[8], colIdx[8];
#pragma unroll
    for (int i = 0; i < 8; ++i) {
        rowIdx[i] = (i < 4) ? (4 * ty + i) : (64 + 4 * ty + (i - 4));
        ar[i] = asum[m0 + rowIdx[i]];
    }
#pragma unroll
    for (int j = 0; j < 8; ++j) {
        colIdx[j] = (j < 4) ? (4 * tx + j) : (64 + 4 * tx + (j - 4));
        bc[j] = bsum[n0 + colIdx[j]];
    }
#pragma unroll
    for (int i = 0; i < 8; ++i) {
        unsigned long long best = 0xFFFFFFFFFFFFFFFFull;
#pragma unroll
        for (int j = 0; j < 8; ++j) {
            float ts = __fadd_rn(ar[i], bc[j]);
            float d = __fsub_rn(ts, __fmul_rn(2.0f, acc[i][j]));
            unsigned long long p = ((unsigned long long)__float_as_uint(d) << 32) |
                                   (unsigned)(n0 + colIdx[j]);
            best = (p < best) ? p : best;
        }
#pragma unroll
        for (int m = 1; m <= 8; m <<= 1) {
            unsigned long long o = shflxor64(best, m);
            best = (o < best) ? o : best;
        }
        if (tx == 0) atomicMin(&packed[m0 + rowIdx[i]], best);
    }
}

__global__ __launch_bounds__(256) void finalize_kernel(
    const float* __restrict__ Z, const float* __restrict__ CB,
    const unsigned long long* __restrict__ packed,
    float* __restrict__ out, float* __restrict__ loss_acc) {
    float* out_zq = out + 2;
    float* out_idx = out + 2 + (size_t)N_ELEM;
    const int lane = threadIdx.x & 63;
    const int wid = (blockIdx.x * blockDim.x + threadIdx.x) >> 6;
    const int nw = (gridDim.x * blockDim.x) >> 6;
    float lsum = 0.0f;
    for (int row = wid; row < M_ROWS; row += nw) {
        unsigned long long pk = packed[row];
        unsigned idx = (unsigned)(pk & 0xFFFFFFFFull);
        if (lane == 0) out_idx[row] = (float)idx;
        const float4 zv = *(const float4*)(Z + (size_t)row * D_DIM + lane * 4);
        const float4 cv = *(const float4*)(CB + (size_t)idx * D_DIM + lane * 4);
        float d0 = __fsub_rn(cv.x, zv.x);
        float d1 = __fsub_rn(cv.y, zv.y);
        float d2 = __fsub_rn(cv.z, zv.z);
        float d3 = __fsub_rn(cv.w, zv.w);
        float2 o0 = make_float2(__fadd_rn(zv.x, d0), __fadd_rn(zv.y, d1));
        float2 o1 = make_float2(__fadd_rn(zv.z, d2), __fadd_rn(zv.w, d3));
        *(float2*)(out_zq + (size_t)row * D_DIM + lane * 4) = o0;
        *(float2*)(out_zq + (size_t)row * D_DIM + lane * 4 + 2) = o1;
        lsum += d0 * d0 + d1 * d1 + d2 * d2 + d3 * d3;
    }
#pragma unroll
    for (int m = 1; m < 64; m <<= 1) lsum += __shfl_xor(lsum, m);
    __shared__ float red[4];
    if (lane == 0) red[threadIdx.x >> 6] = lsum;
    __syncthreads();
    if (threadIdx.x == 0) {
        float s = ((red[0] + red[1]) + (red[2] + red[3]));
        atomicAdd(loss_acc, s);
    }
}

// ===========================================================================
extern "C" void kernel_launch(void* const* d_in, const int* in_sizes, int n_in,
                              void* d_out, int out_size, void* d_ws, size_t ws_size,
                              hipStream_t stream) {
    const float* Z = (const float*)d_in[0];    // [17664, 256]
    const float* CB = (const float*)d_in[1];   // [8192, 256]
    float* out = (float*)d_out;
    char* ws = (char*)d_ws;

    const size_t offZb   = 0;                                       // 9,043,968
    const size_t offCb   = offZb + (size_t)M_ROWS * D_DIM * 2;      // +4,194,304
    const size_t offCand = offCb + (size_t)K_CODES * D_DIM * 2;     // +18,087,936
    const size_t offAsum = offCand + (size_t)M_ROWS * 256 * 4;
    const size_t offBsum = offAsum + (size_t)M_ROWS * 4;
    const size_t offLoss = offBsum + (size_t)K_CODES * 4;
    const size_t need    = offLoss + 64;

    if (ws_size >= need) {
        ushort_t* Zb = (ushort_t*)(ws + offZb);
        ushort_t* Cb = (ushort_t*)(ws + offCb);
        unsigned* blockcand = (unsigned*)(ws + offCand);
        float* asum = (float*)(ws + offAsum);
        float* bsum = (float*)(ws + offBsum);
        float* loss_acc = (float*)(ws + offLoss);

        hipLaunchKernelGGL(init_loss_kernel, dim3(1), dim3(64), 0, stream, loss_acc);
        hipLaunchKernelGGL(rowsq_kernel, dim3((M_ROWS + 255) / 256), dim3(256), 0, stream,
                           Z, asum, M_ROWS);
        hipLaunchKernelGGL(rowsq_kernel, dim3((K_CODES + 255) / 256), dim3(256), 0, stream,
                           CB, bsum, K_CODES);
        hipLaunchKernelGGL(tobf16_kernel, dim3(M_ROWS * 32 / 256), dim3(256), 0, stream,
                           Z, Zb, M_ROWS * 32);
        hipLaunchKernelGGL(tobf16_kernel, dim3(K_CODES * 32 / 256), dim3(256), 0, stream,
                           CB, Cb, K_CODES * 32);
        hipLaunchKernelGGL(phase1_kernel, dim3((M_ROWS / 256) * (K_CODES / 256)),
                           dim3(512), 131072, stream, Zb, Cb, bsum, blockcand);
        hipLaunchKernelGGL(phase2_kernel, dim3(M_ROWS / 4), dim3(256), 0, stream,
                           Z, CB, asum, bsum, blockcand, out, loss_acc);
        hipLaunchKernelGGL(write_losses, dim3(1), dim3(1), 0, stream, loss_acc, out);
    } else {
        float* asum = (float*)ws;
        float* bsum = (float*)(ws + (size_t)M_ROWS * 4);
        unsigned long long* packed =
            (unsigned long long*)(ws + (size_t)M_ROWS * 4 + (size_t)K_CODES * 4);
        float* loss_acc =
            (float*)(ws + (size_t)M_ROWS * 4 + (size_t)K_CODES * 4 + (size_t)M_ROWS * 8);

        hipLaunchKernelGGL(init_kernel, dim3((M_ROWS + 255) / 256), dim3(256), 0, stream,
                           packed, loss_acc);
        hipLaunchKernelGGL(rowsq_kernel, dim3((M_ROWS + 255) / 256), dim3(256), 0, stream,
                           Z, asum, M_ROWS);
        hipLaunchKernelGGL(rowsq_kernel, dim3((K_CODES + 255) / 256), dim3(256), 0, stream,
                           CB, bsum, K_CODES);
        hipLaunchKernelGGL(gemm_argmin_kernel, dim3((M_ROWS / BM) * (K_CODES / BN)),
                           dim3(256), 0, stream, Z, CB, asum, bsum, packed);
        hipLaunchKernelGGL(finalize_kernel, dim3(512), dim3(256), 0, stream,
                           Z, CB, packed, out, loss_acc);
        hipLaunchKernelGGL(write_losses, dim3(1), dim3(1), 0, stream, loss_acc, out);
    }
}

// Round 6
// 176.058 us; speedup vs baseline: 2.8242x; 1.1151x over previous
//
#include <hip/hip_runtime.h>
#include <hip/hip_bf16.h>

#define M_ROWS 17664   // B*T = 64*276
#define K_CODES 8192
#define D_DIM 256
#define N_ELEM 4521984 // M_ROWS * 256

typedef unsigned short ushort_t;
typedef __attribute__((ext_vector_type(8))) short short8v;  // 8 bf16 (4 VGPRs)
typedef __attribute__((ext_vector_type(4))) float f32x4;

__device__ __forceinline__ unsigned long long umin64(unsigned long long a, unsigned long long b) { return a < b ? a : b; }
__device__ __forceinline__ unsigned long long umax64(unsigned long long a, unsigned long long b) { return a > b ? a : b; }

__device__ __forceinline__ unsigned long long shflxor64(unsigned long long v, int m) {
    unsigned lo = (unsigned)v, hi = (unsigned)(v >> 32);
    lo = __shfl_xor(lo, m);
    hi = __shfl_xor(hi, m);
    return ((unsigned long long)hi << 32) | lo;
}

__device__ __forceinline__ void gload16(const void* g, void* l) {
    __builtin_amdgcn_global_load_lds((const __attribute__((address_space(1))) void*)g,
                                     (__attribute__((address_space(3))) void*)l, 16, 0, 0);
}

#define RAW_BARRIER() do { asm volatile("" ::: "memory"); \
    __builtin_amdgcn_s_barrier(); asm volatile("" ::: "memory"); } while (0)

// ---------------------------------------------------------------------------
// Fused prep: coalesced read of 32 rows -> bf16 copy + EXACT numpy pairwise
// sum-of-squares (same __fmul_rn/__fadd_rn chain as the verified rowsq).
// LDS stride 257 floats: part-2 row reads are bank-conflict-free.
// ---------------------------------------------------------------------------
__global__ __launch_bounds__(256) void prep_kernel(const float* __restrict__ X,
                                                   ushort_t* __restrict__ Xb,
                                                   float* __restrict__ asum,
                                                   float* __restrict__ loss_acc) {
    __shared__ float S[32][257];
    const int t = threadIdx.x;
    const int r0 = blockIdx.x * 32;
    if (loss_acc != nullptr && blockIdx.x == 0 && t == 0) loss_acc[0] = 0.0f;
#pragma unroll
    for (int it = 0; it < 8; ++it) {
        int idx4 = t + it * 256;          // 0..2047 float4s
        int row = idx4 >> 6;              // 0..31
        int c4 = (idx4 & 63) * 4;
        const float4 v = *(const float4*)(X + (size_t)(r0 + row) * D_DIM + c4);
        float vv[4] = {v.x, v.y, v.z, v.w};
        ushort_t h[4];
#pragma unroll
        for (int j = 0; j < 4; ++j) {
            __hip_bfloat16 b = __float2bfloat16(vv[j]);
            h[j] = *reinterpret_cast<ushort_t*>(&b);
        }
        *(ushort4*)(Xb + (size_t)(r0 + row) * D_DIM + c4) =
            make_ushort4(h[0], h[1], h[2], h[3]);
        S[row][c4 + 0] = v.x; S[row][c4 + 1] = v.y;
        S[row][c4 + 2] = v.z; S[row][c4 + 3] = v.w;
    }
    __syncthreads();
    if (t < 32) {
        float half_sum[2];
#pragma unroll
        for (int h = 0; h < 2; ++h) {
            const float* q = &S[t][h * 128];
            float acc[8];
#pragma unroll
            for (int j = 0; j < 8; ++j) acc[j] = __fmul_rn(q[j], q[j]);
            for (int i = 8; i < 128; i += 8) {
#pragma unroll
                for (int j = 0; j < 8; ++j)
                    acc[j] = __fadd_rn(acc[j], __fmul_rn(q[i + j], q[i + j]));
            }
            float s01 = __fadd_rn(acc[0], acc[1]);
            float s23 = __fadd_rn(acc[2], acc[3]);
            float s45 = __fadd_rn(acc[4], acc[5]);
            float s67 = __fadd_rn(acc[6], acc[7]);
            half_sum[h] = __fadd_rn(__fadd_rn(s01, s23), __fadd_rn(s45, s67));
        }
        asum[r0 + t] = __fadd_rn(half_sum[0], half_sum[1]);
    }
}

// ---------------------------------------------------------------------------
// Phase 1: bf16 MFMA GEMM (Keff=256), 256x256 tile, 8 waves (2Mz x 4Ncb),
// BK=64, double-buffered 128KiB LDS, m201-style PHASED schedule: per K-tile,
// 4 phases of {ds_read subtile + 2 gload_lds(next tile) -> s_barrier ->
// setprio(1) -> 16 MFMA -> setprio(0) -> s_barrier}; tile boundary =
// vmcnt(0)+barrier (only next tile's 8 loads in flight, issued >=2 phases
// earlier). Swizzle & numerics identical to the verified round-5 kernel.
// Epilogue: per-wn top-2 -> LDS -> exact per-256-col-tile top-2 ->
// blockcand[M][32][2] u32 (embedded d_rel floats with 13-bit col index).
// ---------------------------------------------------------------------------
__global__ __launch_bounds__(512, 2) void phase1_kernel(
    const ushort_t* __restrict__ Zb,   // [M][256] bf16 bits
    const ushort_t* __restrict__ Cb,   // [K][256] bf16 bits
    const float* __restrict__ bsum,
    unsigned* __restrict__ blockcand) {
    extern __shared__ ushort_t lds[];  // 131072 B: As[2][16384], Bs[2][16384]
    ushort_t* Asl = lds;               // z tiles
    ushort_t* Bsl = lds + 32768;       // cb tiles

    const int t = threadIdx.x;
    const int wid = t >> 6, lane = t & 63;
    const int wm = wid >> 2, wn = wid & 3;

    // XCD-grouped mapping (bijective: 2208 = 8 * 276)
    const int bid = blockIdx.x;
    const int xcd = bid & 7, jb = bid >> 3;
    const int bn = (xcd << 2) + (jb & 3);
    const int bm = jb >> 2;
    const int m0 = bm * 256, n0 = bn * 256;

    f32x4 acc[4][8];
#pragma unroll
    for (int i = 0; i < 4; ++i)
#pragma unroll
        for (int jj = 0; jj < 8; ++jj) acc[i][jj] = (f32x4){0.f, 0.f, 0.f, 0.f};

    // staging source (pre-swizzled slot; linear gload_lds dest, rule #21)
    const int sq8 = ((lane & 7) ^ (lane >> 3)) * 8;      // shorts
    const ushort_t* zsrc = Zb + (size_t)(m0 + wid * 32 + (lane >> 3)) * 256 + sq8;
    const ushort_t* csrc = Cb + (size_t)(n0 + wid * 32 + (lane >> 3)) * 256 + sq8;
    const int ldst = (wid * 32) * 64;                    // shorts, + i*512

    // fragment read geometry
    const int fr = lane & 15, x7 = lane & 7, q = lane >> 4;

    // ---- prologue: stage K-tile 0 -> buf 0 ----
#pragma unroll
    for (int i = 0; i < 4; ++i) {
        gload16(zsrc + (size_t)i * 2048, Asl + ldst + i * 512);
        gload16(csrc + (size_t)i * 2048, Bsl + ldst + i * 512);
    }
    asm volatile("s_waitcnt vmcnt(0)" ::: "memory");
    RAW_BARRIER();

    // ---- main loop: 4 K-tiles x 4 phases ----
#pragma unroll
    for (int t4 = 0; t4 < 4; ++t4) {
        const int buf = t4 & 1;
        const ushort_t* Az = Asl + buf * 16384;
        const ushort_t* Bc = Bsl + buf * 16384;
        const int ob = (buf ^ 1) * 16384;
        const int kc = (t4 + 1) * 64;                    // shorts
#pragma unroll
        for (int ks = 0; ks < 2; ++ks) {
            const int phys = ((q + ks * 4) ^ x7) * 8;    // shorts
            short8v acb[4];
#pragma unroll
            for (int mi = 0; mi < 4; ++mi)
                acb[mi] = *(const short8v*)(Bc + (wn * 64 + mi * 16 + fr) * 64 + phys);
#pragma unroll
            for (int h = 0; h < 2; ++h) {
                short8v bz[4];
#pragma unroll
                for (int nj = 0; nj < 4; ++nj)
                    bz[nj] = *(const short8v*)(Az + (wm * 128 + (h * 4 + nj) * 16 + fr) * 64 + phys);
                if (t4 < 3) {
                    const int i0 = ks * 2 + h;           // 2 gloads per phase
                    gload16(zsrc + (size_t)i0 * 2048 + kc, Asl + ob + ldst + i0 * 512);
                    gload16(csrc + (size_t)i0 * 2048 + kc, Bsl + ob + ldst + i0 * 512);
                }
                RAW_BARRIER();
                __builtin_amdgcn_s_setprio(1);
#pragma unroll
                for (int mi = 0; mi < 4; ++mi)
#pragma unroll
                    for (int nj = 0; nj < 4; ++nj)
                        acc[mi][h * 4 + nj] = __builtin_amdgcn_mfma_f32_16x16x32_bf16(
                            acb[mi], bz[nj], acc[mi][h * 4 + nj], 0, 0, 0);
                __builtin_amdgcn_s_setprio(0);
                RAW_BARRIER();
            }
        }
        if (t4 < 3) {  // tile boundary: only next tile's 8 loads outstanding
            asm volatile("s_waitcnt vmcnt(0)" ::: "memory");
            RAW_BARRIER();
        }
    }

    // ---- epilogue: per z-row top-2 over this wave's 64 cb-cols -> LDS ----
    unsigned* cand = (unsigned*)Asl;   // [256 rows][4 wn][2] u32 = 8 KiB
    const int colb = n0 + wn * 64 + q * 4;
    float bc16[16];
#pragma unroll
    for (int mi = 0; mi < 4; ++mi)
#pragma unroll
        for (int r = 0; r < 4; ++r)
            bc16[mi * 4 + r] = bsum[colb + mi * 16 + r];

    const float INF = __uint_as_float(0x7f800000u);
#pragma unroll
    for (int nj = 0; nj < 8; ++nj) {
        float m1 = INF, m2 = INF;
#pragma unroll
        for (int mi = 0; mi < 4; ++mi)
#pragma unroll
            for (int r = 0; r < 4; ++r) {
                float dm = __builtin_fmaf(-2.0f, acc[mi][nj][r], bc16[mi * 4 + r]);
                unsigned e = (__float_as_uint(dm) & 0xFFFFE000u) |
                             (unsigned)(colb + mi * 16 + r);
                float fe = __uint_as_float(e);
                m2 = __builtin_amdgcn_fmed3f(m1, m2, fe);
                m1 = fminf(m1, fe);
            }
#pragma unroll
        for (int s = 16; s <= 32; s <<= 1) {
            float o1 = __shfl_xor(m1, s);
            float o2 = __shfl_xor(m2, s);
            float nm2 = fminf(fmaxf(m1, o1), fminf(m2, o2));
            m1 = fminf(m1, o1);
            m2 = nm2;
        }
        if (q == 0) {
            int zr = wm * 128 + nj * 16 + fr;            // 0..255 local row
            cand[zr * 8 + wn * 2 + 0] = __float_as_uint(m1);
            cand[zr * 8 + wn * 2 + 1] = __float_as_uint(m2);
        }
    }
    RAW_BARRIER();
    // exact top-2 of the 4 groups' top-2s = top-2 of this 256-col tile
    if (t < 256) {
        float b1 = INF, b2 = INF;
#pragma unroll
        for (int j = 0; j < 8; ++j) {
            float f = __uint_as_float(cand[t * 8 + j]);
            b2 = __builtin_amdgcn_fmed3f(b1, b2, f);
            b1 = fminf(b1, f);
        }
        *(uint2*)(blockcand + (size_t)(m0 + t) * 64 + bn * 2) =
            make_uint2(__float_as_uint(b1), __float_as_uint(b2));
    }
}

// ---------------------------------------------------------------------------
// Phase 2 + finalize: per row (one wave), scan 64 u32 candidates, threshold
// at dmin_rel + 5e-4, exact fp32 np-structured distance per survivor, index
// tiebreak, then z_q_st / min_idx / loss exactly as the verified path.
// ---------------------------------------------------------------------------
__global__ __launch_bounds__(256) void phase2_kernel(
    const float* __restrict__ Z, const float* __restrict__ CB,
    const float* __restrict__ asum, const float* __restrict__ bsum,
    const unsigned* __restrict__ blockcand,
    float* __restrict__ out, float* __restrict__ loss_acc) {
    float* out_zq = out + 2;
    float* out_idx = out + 2 + (size_t)N_ELEM;
    const int lane = threadIdx.x & 63;
    const int w = threadIdx.x >> 6;
    const int row = blockIdx.x * 4 + w;
    float lsum = 0.0f;

    if (row < M_ROWS) {
        const unsigned e = blockcand[(size_t)row * 64 + lane];
        const float f = __uint_as_float(e);
        float mn = f;
#pragma unroll
        for (int s = 1; s < 64; s <<= 1) mn = fminf(mn, __shfl_xor(mn, s));
        const float thr = mn + 5.0e-4f;
        unsigned long long mask = __ballot(f <= thr);

        const float4 zv = *(const float4*)(Z + (size_t)row * D_DIM + lane * 4);
        float ar = asum[row];
        unsigned long long best = 0xFFFFFFFFFFFFFFFFull;

        while (mask) {
            int b = __ffsll(mask) - 1;
            mask &= mask - 1;
            unsigned e2 = __shfl(e, b);
            unsigned col = e2 & 8191u;
            const float4 cv = *(const float4*)(CB + (size_t)col * D_DIM + lane * 4);
            float s = __fmul_rn(zv.x, cv.x);
            s = __builtin_fmaf(zv.y, cv.y, s);
            s = __builtin_fmaf(zv.z, cv.z, s);
            s = __builtin_fmaf(zv.w, cv.w, s);
#pragma unroll
            for (int m = 1; m < 64; m <<= 1) s += __shfl_xor(s, m);
            float d = __fsub_rn(__fadd_rn(ar, bsum[col]), __fmul_rn(2.0f, s));
            unsigned long long p = ((unsigned long long)__float_as_uint(d) << 32) | col;
            best = umin64(best, p);
        }

        unsigned wincol = (unsigned)best;
        if (lane == 0) out_idx[row] = (float)wincol;
        const float4 cv = *(const float4*)(CB + (size_t)wincol * D_DIM + lane * 4);
        float d0 = __fsub_rn(cv.x, zv.x);
        float d1 = __fsub_rn(cv.y, zv.y);
        float d2 = __fsub_rn(cv.z, zv.z);
        float d3 = __fsub_rn(cv.w, zv.w);
        float2 o0 = make_float2(__fadd_rn(zv.x, d0), __fadd_rn(zv.y, d1));
        float2 o1 = make_float2(__fadd_rn(zv.z, d2), __fadd_rn(zv.w, d3));
        *(float2*)(out_zq + (size_t)row * D_DIM + lane * 4) = o0;
        *(float2*)(out_zq + (size_t)row * D_DIM + lane * 4 + 2) = o1;
        lsum = d0 * d0 + d1 * d1 + d2 * d2 + d3 * d3;
    }
#pragma unroll
    for (int m = 1; m < 64; m <<= 1) lsum += __shfl_xor(lsum, m);
    __shared__ float red[4];
    if (lane == 0) red[w] = lsum;
    __syncthreads();
    if (threadIdx.x == 0) {
        float s = ((red[0] + red[1]) + (red[2] + red[3]));
        atomicAdd(loss_acc, s);
    }
}

__global__ void write_losses(const float* __restrict__ loss_acc,
                             float* __restrict__ out) {
    float l = __fdiv_rn(loss_acc[0], (float)N_ELEM);
    out[0] = l;
    out[1] = l;
}

// ======================= fallback path (fp32 VALU, verified) ================
#define BM 128
#define BN 128
#define BK 32
#define LDT 132

__global__ void rowsq_kernel(const float* __restrict__ X,
                             float* __restrict__ out, int rows) {
    int r = blockIdx.x * blockDim.x + threadIdx.x;
    if (r >= rows) return;
    const float* p = X + (size_t)r * D_DIM;
    float half_sum[2];
#pragma unroll
    for (int h = 0; h < 2; ++h) {
        const float* q = p + h * 128;
        float acc[8];
#pragma unroll
        for (int j = 0; j < 8; ++j) acc[j] = __fmul_rn(q[j], q[j]);
        for (int i = 8; i < 128; i += 8) {
#pragma unroll
            for (int j = 0; j < 8; ++j)
                acc[j] = __fadd_rn(acc[j], __fmul_rn(q[i + j], q[i + j]));
        }
        float s01 = __fadd_rn(acc[0], acc[1]);
        float s23 = __fadd_rn(acc[2], acc[3]);
        float s45 = __fadd_rn(acc[4], acc[5]);
        float s67 = __fadd_rn(acc[6], acc[7]);
        half_sum[h] = __fadd_rn(__fadd_rn(s01, s23), __fadd_rn(s45, s67));
    }
    out[r] = __fadd_rn(half_sum[0], half_sum[1]);
}

__global__ void init_kernel(unsigned long long* __restrict__ packed,
                            float* __restrict__ loss_acc) {
    int i = blockIdx.x * blockDim.x + threadIdx.x;
    if (i < M_ROWS) packed[i] = 0xFFFFFFFFFFFFFFFFull;
    if (i == 0) loss_acc[0] = 0.0f;
}

__global__ __launch_bounds__(256) void gemm_argmin_kernel(
    const float* __restrict__ Z, const float* __restrict__ CB,
    const float* __restrict__ asum, const float* __restrict__ bsum,
    unsigned long long* __restrict__ packed) {
    __shared__ float As[BK][LDT];
    __shared__ float Bs[BK][LDT];
    const int bid = blockIdx.x;
    const int bm = bid >> 6, bn = bid & 63;
    const int m0 = bm * BM, n0 = bn * BN;
    const int t = threadIdx.x;
    const int ty = t >> 4, tx = t & 15;
    float acc[8][8];
#pragma unroll
    for (int i = 0; i < 8; ++i)
#pragma unroll
        for (int j = 0; j < 8; ++j) acc[i][j] = 0.0f;
    for (int k0 = 0; k0 < D_DIM; k0 += BK) {
#pragma unroll
        for (int i = 0; i < 4; ++i) {
            int idx = t + i * 256;
            int row = idx >> 3, kq = idx & 7;
            const float4 av = *(const float4*)(Z + (size_t)(m0 + row) * D_DIM + k0 + kq * 4);
            As[kq * 4 + 0][row] = av.x; As[kq * 4 + 1][row] = av.y;
            As[kq * 4 + 2][row] = av.z; As[kq * 4 + 3][row] = av.w;
            const float4 bv = *(const float4*)(CB + (size_t)(n0 + row) * D_DIM + k0 + kq * 4);
            Bs[kq * 4 + 0][row] = bv.x; Bs[kq * 4 + 1][row] = bv.y;
            Bs[kq * 4 + 2][row] = bv.z; Bs[kq * 4 + 3][row] = bv.w;
        }
        __syncthreads();
#pragma unroll
        for (int k = 0; k < BK; ++k) {
            float af[8], bf[8];
            *(float4*)(af)     = *(const float4*)(&As[k][ty * 4]);
            *(float4*)(af + 4) = *(const float4*)(&As[k][64 + ty * 4]);
            *(float4*)(bf)     = *(const float4*)(&Bs[k][tx * 4]);
            *(float4*)(bf + 4) = *(const float4*)(&Bs[k][64 + tx * 4]);
#pragma unroll
            for (int i = 0; i < 8; ++i)
#pragma unroll
                for (int j = 0; j < 8; ++j)
                    acc[i][j] = __builtin_fmaf(af[i], bf[j], acc[i][j]);
        }
        __syncthreads();
    }
    float ar[8], bc[8];
    int rowIdx[8], colIdx[8];
#pragma unroll
    for (int i = 0; i < 8; ++i) {
        rowIdx[i] = (i < 4) ? (4 * ty + i) : (64 + 4 * ty + (i - 4));
        ar[i] = asum[m0 + rowIdx[i]];
    }
#pragma unroll
    for (int j = 0; j < 8; ++j) {
        colIdx[j] = (j < 4) ? (4 * tx + j) : (64 + 4 * tx + (j - 4));
        bc[j] = bsum[n0 + colIdx[j]];
    }
#pragma unroll
    for (int i = 0; i < 8; ++i) {
        unsigned long long best = 0xFFFFFFFFFFFFFFFFull;
#pragma unroll
        for (int j = 0; j < 8; ++j) {
            float ts = __fadd_rn(ar[i], bc[j]);
            float d = __fsub_rn(ts, __fmul_rn(2.0f, acc[i][j]));
            unsigned long long p = ((unsigned long long)__float_as_uint(d) << 32) |
                                   (unsigned)(n0 + colIdx[j]);
            best = (p < best) ? p : best;
        }
#pragma unroll
        for (int m = 1; m <= 8; m <<= 1) {
            unsigned long long o = shflxor64(best, m);
            best = (o < best) ? o : best;
        }
        if (tx == 0) atomicMin(&packed[m0 + rowIdx[i]], best);
    }
}

__global__ __launch_bounds__(256) void finalize_kernel(
    const float* __restrict__ Z, const float* __restrict__ CB,
    const unsigned long long* __restrict__ packed,
    float* __restrict__ out, float* __restrict__ loss_acc) {
    float* out_zq = out + 2;
    float* out_idx = out + 2 + (size_t)N_ELEM;
    const int lane = threadIdx.x & 63;
    const int wid = (blockIdx.x * blockDim.x + threadIdx.x) >> 6;
    const int nw = (gridDim.x * blockDim.x) >> 6;
    float lsum = 0.0f;
    for (int row = wid; row < M_ROWS; row += nw) {
        unsigned long long pk = packed[row];
        unsigned idx = (unsigned)(pk & 0xFFFFFFFFull);
        if (lane == 0) out_idx[row] = (float)idx;
        const float4 zv = *(const float4*)(Z + (size_t)row * D_DIM + lane * 4);
        const float4 cv = *(const float4*)(CB + (size_t)idx * D_DIM + lane * 4);
        float d0 = __fsub_rn(cv.x, zv.x);
        float d1 = __fsub_rn(cv.y, zv.y);
        float d2 = __fsub_rn(cv.z, zv.z);
        float d3 = __fsub_rn(cv.w, zv.w);
        float2 o0 = make_float2(__fadd_rn(zv.x, d0), __fadd_rn(zv.y, d1));
        float2 o1 = make_float2(__fadd_rn(zv.z, d2), __fadd_rn(zv.w, d3));
        *(float2*)(out_zq + (size_t)row * D_DIM + lane * 4) = o0;
        *(float2*)(out_zq + (size_t)row * D_DIM + lane * 4 + 2) = o1;
        lsum += d0 * d0 + d1 * d1 + d2 * d2 + d3 * d3;
    }
#pragma unroll
    for (int m = 1; m < 64; m <<= 1) lsum += __shfl_xor(lsum, m);
    __shared__ float red[4];
    if (lane == 0) red[threadIdx.x >> 6] = lsum;
    __syncthreads();
    if (threadIdx.x == 0) {
        float s = ((red[0] + red[1]) + (red[2] + red[3]));
        atomicAdd(loss_acc, s);
    }
}

// ===========================================================================
extern "C" void kernel_launch(void* const* d_in, const int* in_sizes, int n_in,
                              void* d_out, int out_size, void* d_ws, size_t ws_size,
                              hipStream_t stream) {
    const float* Z = (const float*)d_in[0];    // [17664, 256]
    const float* CB = (const float*)d_in[1];   // [8192, 256]
    float* out = (float*)d_out;
    char* ws = (char*)d_ws;

    const size_t offZb   = 0;                                   // 9,043,968
    const size_t offCb   = offZb + (size_t)M_ROWS * D_DIM * 2;  // +4,194,304
    const size_t offCand = offCb + (size_t)K_CODES * D_DIM * 2; // +4,521,984
    const size_t offAsum = offCand + (size_t)M_ROWS * 64 * 4;
    const size_t offBsum = offAsum + (size_t)M_ROWS * 4;
    const size_t offLoss = offBsum + (size_t)K_CODES * 4;
    const size_t need    = offLoss + 64;

    if (ws_size >= need) {
        ushort_t* Zb = (ushort_t*)(ws + offZb);
        ushort_t* Cb = (ushort_t*)(ws + offCb);
        unsigned* blockcand = (unsigned*)(ws + offCand);
        float* asum = (float*)(ws + offAsum);
        float* bsum = (float*)(ws + offBsum);
        float* loss_acc = (float*)(ws + offLoss);

        hipLaunchKernelGGL(prep_kernel, dim3(M_ROWS / 32), dim3(256), 0, stream,
                           Z, Zb, asum, loss_acc);
        hipLaunchKernelGGL(prep_kernel, dim3(K_CODES / 32), dim3(256), 0, stream,
                           CB, Cb, bsum, (float*)nullptr);
        hipLaunchKernelGGL(phase1_kernel, dim3((M_ROWS / 256) * (K_CODES / 256)),
                           dim3(512), 131072, stream, Zb, Cb, bsum, blockcand);
        hipLaunchKernelGGL(phase2_kernel, dim3(M_ROWS / 4), dim3(256), 0, stream,
                           Z, CB, asum, bsum, blockcand, out, loss_acc);
        hipLaunchKernelGGL(write_losses, dim3(1), dim3(1), 0, stream, loss_acc, out);
    } else {
        float* asum = (float*)ws;
        float* bsum = (float*)(ws + (size_t)M_ROWS * 4);
        unsigned long long* packed =
            (unsigned long long*)(ws + (size_t)M_ROWS * 4 + (size_t)K_CODES * 4);
        float* loss_acc =
            (float*)(ws + (size_t)M_ROWS * 4 + (size_t)K_CODES * 4 + (size_t)M_ROWS * 8);

        hipLaunchKernelGGL(init_kernel, dim3((M_ROWS + 255) / 256), dim3(256), 0, stream,
                           packed, loss_acc);
        hipLaunchKernelGGL(rowsq_kernel, dim3((M_ROWS + 255) / 256), dim3(256), 0, stream,
                           Z, asum, M_ROWS);
        hipLaunchKernelGGL(rowsq_kernel, dim3((K_CODES + 255) / 256), dim3(256), 0, stream,
                           CB, bsum, K_CODES);
        hipLaunchKernelGGL(gemm_argmin_kernel, dim3((M_ROWS / BM) * (K_CODES / BN)),
                           dim3(256), 0, stream, Z, CB, asum, bsum, packed);
        hipLaunchKernelGGL(finalize_kernel, dim3(512), dim3(256), 0, stream,
                           Z, CB, packed, out, loss_acc);
        hipLaunchKernelGGL(write_losses, dim3(1), dim3(1), 0, stream, loss_acc, out);
    }
}